// Round 1
// baseline (605.736 us; speedup 1.0000x reference)
//
#include <hip/hip_runtime.h>
#include <cstdint>
#include <cstddef>

// Problem: B=4, S=2048, D=1024, U=1024 self-attention, fp32 in/out.
// Strategy: split-bf16 (hi/lo) 3-term GEMMs for QKV and Q.K^T (logit precision),
// plain bf16 for P.V. One NT-GEMM template (128x128 tile, BK=32, mfma 16x16x32 bf16).

typedef unsigned short ushort_t;
typedef __attribute__((ext_vector_type(8))) short short8;
typedef __attribute__((ext_vector_type(4))) float floatx4;

// ---------- bf16 helpers (bit-level, round-to-nearest-even) ----------
__device__ inline ushort_t f2bf(float f) {
  unsigned u = __float_as_uint(f);
  unsigned r = (u + 0x7FFFu + ((u >> 16) & 1u)) >> 16;
  return (ushort_t)r;
}
__device__ inline float bf2f(ushort_t h) {
  return __uint_as_float(((unsigned)h) << 16);
}

// ---------- constants ----------
#define MB 4
#define SS 2048
#define DD 1024
#define UU 1024
#define MX 8192       // B*S
#define KCAT 3072     // 3*D (split-concatenated K dim)

// ws byte offsets
#define XCAT_OFF 0UL                  // ushort [8192][3072] = 50331648 B
#define WT_OFF   50331648UL           // ushort 3 x [1024][3072] = 18874368 B
#define S_OFF    0UL                  // float [4][2048][2048] = 67108864 B (reuses XCAT+WT after QKV)
#define QCAT_OFF 69206016UL           // ushort [8192][3072]
#define KCAT_OFF 119537664UL          // ushort [8192][3072]
#define VT_OFF   169869312UL          // ushort [4][1024][2048] = 16777216 B
#define WS_NEED  186646528UL

// ---------- K1a: split inputs X -> Xcat = [hi | hi | lo] ----------
__global__ __launch_bounds__(256) void k_split_x(const float* __restrict__ X,
                                                 ushort_t* __restrict__ xcat) {
  long long i = (long long)blockIdx.x * 256 + threadIdx.x;  // over 8192*1024
  float x = X[i];
  ushort_t hi = f2bf(x);
  ushort_t lo = f2bf(x - bf2f(hi));
  long long row = i >> 10;
  int col = (int)(i & 1023);
  ushort_t* r = xcat + row * KCAT;
  r[col] = hi;
  r[col + 1024] = hi;
  r[col + 2048] = lo;
}

// ---------- K1b: transpose + split W -> WT_cat = [hi | lo | hi] per weight ----------
__global__ __launch_bounds__(256) void k_split_wt(const float* __restrict__ Wq,
                                                  const float* __restrict__ Wk,
                                                  const float* __restrict__ Wv,
                                                  ushort_t* __restrict__ wt) {
  __shared__ float tile[64][65];
  const float* W = (blockIdx.z == 0) ? Wq : ((blockIdx.z == 1) ? Wk : Wv);
  ushort_t* out = wt + (size_t)blockIdx.z * 1024 * KCAT;
  int d0 = blockIdx.y * 64, u0 = blockIdx.x * 64;
  int t = threadIdx.x;
  int tr = t >> 6, tc = t & 63;  // 4 rows x 64 cols per pass
  for (int r = 0; r < 64; r += 4)
    tile[r + tr][tc] = W[(size_t)(d0 + r + tr) * 1024 + (u0 + tc)];
  __syncthreads();
  for (int r = 0; r < 64; r += 4) {
    int urow = r + tr, dcol = tc;
    float x = tile[dcol][urow];  // = W[d0+dcol][u0+urow] = WT[u0+urow][d0+dcol]
    ushort_t hi = f2bf(x), lo = f2bf(x - bf2f(hi));
    ushort_t* o = out + (size_t)(u0 + urow) * KCAT + d0;
    o[dcol] = hi;
    o[dcol + 1024] = lo;
    o[dcol + 2048] = hi;
  }
}

// ---------- GEMM template: C[m][n] = sum_k A[m][k] * Bt[n][k] ----------
// 128x128 tile, BK=32, 4 waves, 4x4 16x16x32 bf16 mfma per wave.
enum { EP_F32 = 0, EP_QCAT = 1, EP_KCAT = 2, EP_VT = 3 };

template <int MODE>
__global__ __launch_bounds__(256) void k_gemm(
    const ushort_t* __restrict__ A, long long aBatch, int lda,
    const ushort_t* __restrict__ Bt, long long bBatch, int ldb,
    void* __restrict__ Cout, long long cBatch, int ldc, int K) {
  __shared__ __align__(16) ushort_t As[128 * 32];
  __shared__ __align__(16) ushort_t Bs[128 * 32];
  const int t = threadIdx.x;
  const int z = blockIdx.z;
  A += (long long)z * aBatch;
  Bt += (long long)z * bBatch;
  const int m0 = blockIdx.y * 128, n0 = blockIdx.x * 128;

  const int w = t >> 6, l = t & 63;
  const int lr = l & 15, quad = l >> 4;
  const int wm = (w >> 1) * 64, wn = (w & 1) * 64;

  const floatx4 fz = {0.f, 0.f, 0.f, 0.f};
  floatx4 acc[4][4];
#pragma unroll
  for (int i = 0; i < 4; i++)
#pragma unroll
    for (int j = 0; j < 4; j++) acc[i][j] = fz;

  // staging: 512 chunks of 16B per tile; thread t handles chunks t and t+256
  const int c0 = t, c1 = t + 256;
  const ushort_t* Ap0 = A + (long long)(m0 + (c0 >> 2)) * lda + (c0 & 3) * 8;
  const ushort_t* Ap1 = A + (long long)(m0 + (c1 >> 2)) * lda + (c1 & 3) * 8;
  const ushort_t* Bp0 = Bt + (long long)(n0 + (c0 >> 2)) * ldb + (c0 & 3) * 8;
  const ushort_t* Bp1 = Bt + (long long)(n0 + (c1 >> 2)) * ldb + (c1 & 3) * 8;

  for (int kb = 0; kb < K; kb += 32) {
    uint4 a0 = *(const uint4*)(Ap0 + kb);
    uint4 a1 = *(const uint4*)(Ap1 + kb);
    uint4 b0 = *(const uint4*)(Bp0 + kb);
    uint4 b1 = *(const uint4*)(Bp1 + kb);
    __syncthreads();  // prior iter's frag reads done before overwrite
    *(uint4*)&As[c0 * 8] = a0;
    *(uint4*)&As[c1 * 8] = a1;
    *(uint4*)&Bs[c0 * 8] = b0;
    *(uint4*)&Bs[c1 * 8] = b1;
    __syncthreads();
    short8 af[4], bfg[4];
#pragma unroll
    for (int i = 0; i < 4; i++) {
      af[i] = *(const short8*)&As[(wm + i * 16 + lr) * 32 + quad * 8];
      bfg[i] = *(const short8*)&Bs[(wn + i * 16 + lr) * 32 + quad * 8];
    }
#pragma unroll
    for (int i = 0; i < 4; i++)
#pragma unroll
      for (int j = 0; j < 4; j++)
        acc[i][j] = __builtin_amdgcn_mfma_f32_16x16x32_bf16(af[i], bfg[j], acc[i][j], 0, 0, 0);
  }

  // epilogue: D[row = quad*4 + r][col = lr] per (i,j) subtile
#pragma unroll
  for (int i = 0; i < 4; i++) {
#pragma unroll
    for (int j = 0; j < 4; j++) {
#pragma unroll
      for (int r = 0; r < 4; r++) {
        int grow = m0 + wm + i * 16 + quad * 4 + r;
        int gcol = n0 + wn + j * 16 + lr;
        float v = acc[i][j][r];
        if (MODE == EP_F32) {
          float* C = (float*)Cout + (long long)z * cBatch;
          C[(long long)grow * ldc + gcol] = v;
        } else if (MODE == EP_QCAT || MODE == EP_KCAT) {
          ushort_t* C = (ushort_t*)Cout;
          ushort_t hi = f2bf(v), lo = f2bf(v - bf2f(hi));
          ushort_t* p = C + (long long)grow * KCAT;
          if (MODE == EP_QCAT) {
            p[gcol] = hi; p[gcol + 1024] = hi; p[gcol + 2048] = lo;
          } else {
            p[gcol] = hi; p[gcol + 1024] = lo; p[gcol + 2048] = hi;
          }
        } else {  // EP_VT: V^T[b][u][s] = V[b*2048+s][u]
          ushort_t* C = (ushort_t*)Cout;
          int b = grow >> 11, s = grow & 2047;
          C[((long long)b * 1024 + gcol) * 2048 + s] = f2bf(v);
        }
      }
    }
  }
}

// ---------- softmax, in place: S row (fp32[2048]) -> P row (bf16[2048]) ----------
__global__ __launch_bounds__(256) void k_softmax(float* __restrict__ Sbuf) {
  long long row = blockIdx.x;  // 0..8191
  float* p = Sbuf + row * 2048;
  int t = threadIdx.x;
  float4 v0 = ((const float4*)p)[t];
  float4 v1 = ((const float4*)p)[t + 256];
  float m = fmaxf(fmaxf(fmaxf(v0.x, v0.y), fmaxf(v0.z, v0.w)),
                  fmaxf(fmaxf(v1.x, v1.y), fmaxf(v1.z, v1.w)));
  for (int off = 32; off; off >>= 1) m = fmaxf(m, __shfl_xor(m, off));
  __shared__ float red[8];
  int wv = t >> 6, ln = t & 63;
  if (ln == 0) red[wv] = m;
  __syncthreads();
  m = fmaxf(fmaxf(red[0], red[1]), fmaxf(red[2], red[3]));
  float e0 = __expf(v0.x - m), e1 = __expf(v0.y - m), e2 = __expf(v0.z - m), e3 = __expf(v0.w - m);
  float e4 = __expf(v1.x - m), e5 = __expf(v1.y - m), e6 = __expf(v1.z - m), e7 = __expf(v1.w - m);
  float s = ((e0 + e1) + (e2 + e3)) + ((e4 + e5) + (e6 + e7));
  for (int off = 32; off; off >>= 1) s += __shfl_xor(s, off);
  if (ln == 0) red[4 + wv] = s;
  __syncthreads();
  s = (red[4] + red[5]) + (red[6] + red[7]);
  float inv = 1.0f / s;
  ushort_t* op = (ushort_t*)p;
  uint2 w0, w1;
  w0.x = (unsigned)f2bf(e0 * inv) | ((unsigned)f2bf(e1 * inv) << 16);
  w0.y = (unsigned)f2bf(e2 * inv) | ((unsigned)f2bf(e3 * inv) << 16);
  w1.x = (unsigned)f2bf(e4 * inv) | ((unsigned)f2bf(e5 * inv) << 16);
  w1.y = (unsigned)f2bf(e6 * inv) | ((unsigned)f2bf(e7 * inv) << 16);
  ((uint2*)op)[t] = w0;         // elements 4t .. 4t+3
  ((uint2*)op)[t + 256] = w1;   // elements 1024+4t ..
}

// ---------- host launch ----------
extern "C" void kernel_launch(void* const* d_in, const int* in_sizes, int n_in,
                              void* d_out, int out_size, void* d_ws, size_t ws_size,
                              hipStream_t stream) {
  (void)in_sizes; (void)n_in; (void)out_size;
  if (ws_size < WS_NEED) return;  // output stays poisoned -> visible failure

  const float* X = (const float*)d_in[0];
  const float* Wq = (const float*)d_in[1];
  const float* Wk = (const float*)d_in[2];
  const float* Wv = (const float*)d_in[3];
  char* ws = (char*)d_ws;
  ushort_t* xcat = (ushort_t*)(ws + XCAT_OFF);
  ushort_t* wt = (ushort_t*)(ws + WT_OFF);
  float* Sbuf = (float*)(ws + S_OFF);
  ushort_t* qcat = (ushort_t*)(ws + QCAT_OFF);
  ushort_t* kcat = (ushort_t*)(ws + KCAT_OFF);
  ushort_t* vt = (ushort_t*)(ws + VT_OFF);
  float* out = (float*)d_out;

  // 1. split X and W
  k_split_x<<<dim3(MX * DD / 256), dim3(256), 0, stream>>>(X, xcat);
  k_split_wt<<<dim3(16, 16, 3), dim3(256), 0, stream>>>(Wq, Wk, Wv, wt);

  // 2. QKV projections (split-bf16 3-term via K=3072 cat)
  k_gemm<EP_QCAT><<<dim3(8, 64, 1), dim3(256), 0, stream>>>(
      xcat, 0LL, KCAT, wt, 0LL, KCAT, qcat, 0LL, 0, KCAT);
  k_gemm<EP_KCAT><<<dim3(8, 64, 1), dim3(256), 0, stream>>>(
      xcat, 0LL, KCAT, wt + 1024 * KCAT, 0LL, KCAT, kcat, 0LL, 0, KCAT);
  k_gemm<EP_VT><<<dim3(8, 64, 1), dim3(256), 0, stream>>>(
      xcat, 0LL, KCAT, wt + 2 * 1024 * KCAT, 0LL, KCAT, vt, 0LL, 0, KCAT);

  // 3. scores S = Q K^T (split-bf16 3-term), fp32 out
  k_gemm<EP_F32><<<dim3(16, 16, 4), dim3(256), 0, stream>>>(
      qcat, (long long)2048 * KCAT, KCAT, kcat, (long long)2048 * KCAT, KCAT,
      Sbuf, (long long)2048 * 2048, 2048, KCAT);

  // 4. softmax in place (fp32 row -> bf16 row, lda becomes 4096 ushorts)
  k_softmax<<<dim3(8192), dim3(256), 0, stream>>>(Sbuf);

  // 5. O = P V  (plain bf16), fp32 out to d_out
  k_gemm<EP_F32><<<dim3(8, 16, 4), dim3(256), 0, stream>>>(
      (const ushort_t*)Sbuf, (long long)2048 * 4096, 4096,
      vt, (long long)1024 * 2048, 2048,
      out, (long long)2048 * 1024, 1024, 2048);
}

// Round 2
// 581.595 us; speedup vs baseline: 1.0415x; 1.0415x over previous
//
#include <hip/hip_runtime.h>
#include <cstdint>
#include <cstddef>

// Problem: B=4, S=2048, D=1024, U=1024 self-attention, fp32 in/out.
// Strategy: split-bf16 (hi/lo) 3-term GEMMs for QKV and Q.K^T (logit precision),
// plain bf16 for P.V. One NT-GEMM template (128x128 tile, BK=32, mfma 16x16x32 bf16).
// R2: global_load_lds width-16 staging + XOR bank swizzle (source-side permute).

typedef unsigned short ushort_t;
typedef __attribute__((ext_vector_type(8))) short short8;
typedef __attribute__((ext_vector_type(4))) float floatx4;

// ---------- bf16 helpers (bit-level, round-to-nearest-even) ----------
__device__ inline ushort_t f2bf(float f) {
  unsigned u = __float_as_uint(f);
  unsigned r = (u + 0x7FFFu + ((u >> 16) & 1u)) >> 16;
  return (ushort_t)r;
}
__device__ inline float bf2f(ushort_t h) {
  return __uint_as_float(((unsigned)h) << 16);
}

// async 16B global -> LDS (DMA, no VGPR round trip). LDS dest is
// wave-uniform base + lane*16 by HW; pass the wave's base pointer.
__device__ __forceinline__ void gload16(const ushort_t* g, ushort_t* l) {
  __builtin_amdgcn_global_load_lds(
      (const __attribute__((address_space(1))) unsigned int*)g,
      (__attribute__((address_space(3))) unsigned int*)l, 16, 0, 0);
}

// ---------- constants ----------
#define MB 4
#define SS 2048
#define DD 1024
#define UU 1024
#define MX 8192       // B*S
#define KCAT 3072     // 3*D (split-concatenated K dim)

// ws byte offsets
#define XCAT_OFF 0UL                  // ushort [8192][3072] = 50331648 B
#define WT_OFF   50331648UL           // ushort 3 x [1024][3072] = 18874368 B
#define S_OFF    0UL                  // float [4][2048][2048] = 67108864 B (reuses XCAT+WT after QKV)
#define QCAT_OFF 69206016UL           // ushort [8192][3072]
#define KCAT_OFF 119537664UL          // ushort [8192][3072]
#define VT_OFF   169869312UL          // ushort [4][1024][2048] = 16777216 B
#define WS_NEED  186646528UL

// ---------- K1a: split inputs X -> Xcat = [hi | hi | lo] ----------
__global__ __launch_bounds__(256) void k_split_x(const float* __restrict__ X,
                                                 ushort_t* __restrict__ xcat) {
  long long i = (long long)blockIdx.x * 256 + threadIdx.x;  // over 8192*1024
  float x = X[i];
  ushort_t hi = f2bf(x);
  ushort_t lo = f2bf(x - bf2f(hi));
  long long row = i >> 10;
  int col = (int)(i & 1023);
  ushort_t* r = xcat + row * KCAT;
  r[col] = hi;
  r[col + 1024] = hi;
  r[col + 2048] = lo;
}

// ---------- K1b: transpose + split W -> WT_cat = [hi | lo | hi] per weight ----------
__global__ __launch_bounds__(256) void k_split_wt(const float* __restrict__ Wq,
                                                  const float* __restrict__ Wk,
                                                  const float* __restrict__ Wv,
                                                  ushort_t* __restrict__ wt) {
  __shared__ float tile[64][65];
  const float* W = (blockIdx.z == 0) ? Wq : ((blockIdx.z == 1) ? Wk : Wv);
  ushort_t* out = wt + (size_t)blockIdx.z * 1024 * KCAT;
  int d0 = blockIdx.y * 64, u0 = blockIdx.x * 64;
  int t = threadIdx.x;
  int tr = t >> 6, tc = t & 63;  // 4 rows x 64 cols per pass
  for (int r = 0; r < 64; r += 4)
    tile[r + tr][tc] = W[(size_t)(d0 + r + tr) * 1024 + (u0 + tc)];
  __syncthreads();
  for (int r = 0; r < 64; r += 4) {
    int urow = r + tr, dcol = tc;
    float x = tile[dcol][urow];  // = W[d0+dcol][u0+urow] = WT[u0+urow][d0+dcol]
    ushort_t hi = f2bf(x), lo = f2bf(x - bf2f(hi));
    ushort_t* o = out + (size_t)(u0 + urow) * KCAT + d0;
    o[dcol] = hi;
    o[dcol + 1024] = lo;
    o[dcol + 2048] = hi;
  }
}

// ---------- GEMM template: C[m][n] = sum_k A[m][k] * Bt[n][k] ----------
// 128x128 tile, BK=32, 4 waves, 4x4 16x16x32 bf16 mfma per wave.
// LDS tile: 128 rows x 32 ushorts (4 chunks of 16B per row).
// Swizzle: global chunk (row, q) lives at LDS chunk position q ^ ((row>>1)&3).
enum { EP_F32 = 0, EP_QCAT = 1, EP_KCAT = 2, EP_VT = 3 };

template <int MODE>
__global__ __launch_bounds__(256) void k_gemm(
    const ushort_t* __restrict__ A, long long aBatch, int lda,
    const ushort_t* __restrict__ Bt, long long bBatch, int ldb,
    void* __restrict__ Cout, long long cBatch, int ldc, int K) {
  __shared__ __align__(16) ushort_t As[128 * 32];
  __shared__ __align__(16) ushort_t Bs[128 * 32];
  const int t = threadIdx.x;
  const int z = blockIdx.z;
  A += (long long)z * aBatch;
  Bt += (long long)z * bBatch;
  const int m0 = blockIdx.y * 128, n0 = blockIdx.x * 128;

  const int w = t >> 6, l = t & 63;
  const int lr = l & 15, quad = l >> 4;
  const int wm = (w >> 1) * 64, wn = (w & 1) * 64;

  const floatx4 fz = {0.f, 0.f, 0.f, 0.f};
  floatx4 acc[4][4];
#pragma unroll
  for (int i = 0; i < 4; i++)
#pragma unroll
    for (int j = 0; j < 4; j++) acc[i][j] = fz;

  // staging: 512 chunks of 16B per tile; thread t handles chunks t and t+256.
  // LDS chunk c holds global chunk (row = c>>2, gq = (c&3) ^ ((c>>3)&3)).
  const int c0 = t, c1 = t + 256;
  const ushort_t* Ap0 = A + (long long)(m0 + (c0 >> 2)) * lda + (((c0 & 3) ^ ((c0 >> 3) & 3)) * 8);
  const ushort_t* Ap1 = A + (long long)(m0 + (c1 >> 2)) * lda + (((c1 & 3) ^ ((c1 >> 3) & 3)) * 8);
  const ushort_t* Bp0 = Bt + (long long)(n0 + (c0 >> 2)) * ldb + (((c0 & 3) ^ ((c0 >> 3) & 3)) * 8);
  const ushort_t* Bp1 = Bt + (long long)(n0 + (c1 >> 2)) * ldb + (((c1 & 3) ^ ((c1 >> 3) & 3)) * 8);
  // wave-uniform LDS base for each chunk set (lane adds l*16B in HW)
  ushort_t* ldsA0 = &As[(w * 64) * 8];
  ushort_t* ldsA1 = &As[(256 + w * 64) * 8];
  ushort_t* ldsB0 = &Bs[(w * 64) * 8];
  ushort_t* ldsB1 = &Bs[(256 + w * 64) * 8];

  // fragment read: row r = wm/wn + i*16 + lr, chunk pos p = quad ^ ((lr>>1)&3)
  const int p = quad ^ ((lr >> 1) & 3);
  const int aoff = (wm + lr) * 32 + p * 8;
  const int boff = (wn + lr) * 32 + p * 8;

  for (int kb = 0; kb < K; kb += 32) {
    __syncthreads();  // prior iter's frag reads done before overwrite
    gload16(Ap0 + kb, ldsA0);
    gload16(Ap1 + kb, ldsA1);
    gload16(Bp0 + kb, ldsB0);
    gload16(Bp1 + kb, ldsB1);
    __syncthreads();  // barrier drains vmcnt -> LDS data visible
    short8 af[4], bfg[4];
#pragma unroll
    for (int i = 0; i < 4; i++) {
      af[i] = *(const short8*)&As[aoff + i * 512];
      bfg[i] = *(const short8*)&Bs[boff + i * 512];
    }
#pragma unroll
    for (int i = 0; i < 4; i++)
#pragma unroll
      for (int j = 0; j < 4; j++)
        acc[i][j] = __builtin_amdgcn_mfma_f32_16x16x32_bf16(af[i], bfg[j], acc[i][j], 0, 0, 0);
  }

  // epilogue: D[row = quad*4 + r][col = lr] per (i,j) subtile
#pragma unroll
  for (int i = 0; i < 4; i++) {
#pragma unroll
    for (int j = 0; j < 4; j++) {
#pragma unroll
      for (int r = 0; r < 4; r++) {
        int grow = m0 + wm + i * 16 + quad * 4 + r;
        int gcol = n0 + wn + j * 16 + lr;
        float v = acc[i][j][r];
        if (MODE == EP_F32) {
          float* C = (float*)Cout + (long long)z * cBatch;
          C[(long long)grow * ldc + gcol] = v;
        } else if (MODE == EP_QCAT || MODE == EP_KCAT) {
          ushort_t* C = (ushort_t*)Cout;
          ushort_t hi = f2bf(v), lo = f2bf(v - bf2f(hi));
          ushort_t* pq = C + (long long)grow * KCAT;
          if (MODE == EP_QCAT) {
            pq[gcol] = hi; pq[gcol + 1024] = hi; pq[gcol + 2048] = lo;
          } else {
            pq[gcol] = hi; pq[gcol + 1024] = lo; pq[gcol + 2048] = hi;
          }
        } else {  // EP_VT: V^T[b][u][s] = V[b*2048+s][u]
          ushort_t* C = (ushort_t*)Cout;
          int b = grow >> 11, s = grow & 2047;
          C[((long long)b * 1024 + gcol) * 2048 + s] = f2bf(v);
        }
      }
    }
  }
}

// ---------- softmax, in place: S row (fp32[2048]) -> P row (bf16[2048]) ----------
__global__ __launch_bounds__(256) void k_softmax(float* __restrict__ Sbuf) {
  long long row = blockIdx.x;  // 0..8191
  float* p = Sbuf + row * 2048;
  int t = threadIdx.x;
  float4 v0 = ((const float4*)p)[t];
  float4 v1 = ((const float4*)p)[t + 256];
  float m = fmaxf(fmaxf(fmaxf(v0.x, v0.y), fmaxf(v0.z, v0.w)),
                  fmaxf(fmaxf(v1.x, v1.y), fmaxf(v1.z, v1.w)));
  for (int off = 32; off; off >>= 1) m = fmaxf(m, __shfl_xor(m, off));
  __shared__ float red[8];
  int wv = t >> 6, ln = t & 63;
  if (ln == 0) red[wv] = m;
  __syncthreads();
  m = fmaxf(fmaxf(red[0], red[1]), fmaxf(red[2], red[3]));
  float e0 = __expf(v0.x - m), e1 = __expf(v0.y - m), e2 = __expf(v0.z - m), e3 = __expf(v0.w - m);
  float e4 = __expf(v1.x - m), e5 = __expf(v1.y - m), e6 = __expf(v1.z - m), e7 = __expf(v1.w - m);
  float s = ((e0 + e1) + (e2 + e3)) + ((e4 + e5) + (e6 + e7));
  for (int off = 32; off; off >>= 1) s += __shfl_xor(s, off);
  if (ln == 0) red[4 + wv] = s;
  __syncthreads();
  s = (red[4] + red[5]) + (red[6] + red[7]);
  float inv = 1.0f / s;
  ushort_t* op = (ushort_t*)p;
  uint2 w0, w1;
  w0.x = (unsigned)f2bf(e0 * inv) | ((unsigned)f2bf(e1 * inv) << 16);
  w0.y = (unsigned)f2bf(e2 * inv) | ((unsigned)f2bf(e3 * inv) << 16);
  w1.x = (unsigned)f2bf(e4 * inv) | ((unsigned)f2bf(e5 * inv) << 16);
  w1.y = (unsigned)f2bf(e6 * inv) | ((unsigned)f2bf(e7 * inv) << 16);
  ((uint2*)op)[t] = w0;         // elements 4t .. 4t+3
  ((uint2*)op)[t + 256] = w1;   // elements 1024+4t ..
}

// ---------- host launch ----------
extern "C" void kernel_launch(void* const* d_in, const int* in_sizes, int n_in,
                              void* d_out, int out_size, void* d_ws, size_t ws_size,
                              hipStream_t stream) {
  (void)in_sizes; (void)n_in; (void)out_size;
  if (ws_size < WS_NEED) return;  // output stays poisoned -> visible failure

  const float* X = (const float*)d_in[0];
  const float* Wq = (const float*)d_in[1];
  const float* Wk = (const float*)d_in[2];
  const float* Wv = (const float*)d_in[3];
  char* ws = (char*)d_ws;
  ushort_t* xcat = (ushort_t*)(ws + XCAT_OFF);
  ushort_t* wt = (ushort_t*)(ws + WT_OFF);
  float* Sbuf = (float*)(ws + S_OFF);
  ushort_t* qcat = (ushort_t*)(ws + QCAT_OFF);
  ushort_t* kcat = (ushort_t*)(ws + KCAT_OFF);
  ushort_t* vt = (ushort_t*)(ws + VT_OFF);
  float* out = (float*)d_out;

  // 1. split X and W
  k_split_x<<<dim3(MX * DD / 256), dim3(256), 0, stream>>>(X, xcat);
  k_split_wt<<<dim3(16, 16, 3), dim3(256), 0, stream>>>(Wq, Wk, Wv, wt);

  // 2. QKV projections (split-bf16 3-term via K=3072 cat)
  k_gemm<EP_QCAT><<<dim3(8, 64, 1), dim3(256), 0, stream>>>(
      xcat, 0LL, KCAT, wt, 0LL, KCAT, qcat, 0LL, 0, KCAT);
  k_gemm<EP_KCAT><<<dim3(8, 64, 1), dim3(256), 0, stream>>>(
      xcat, 0LL, KCAT, wt + 1024 * KCAT, 0LL, KCAT, kcat, 0LL, 0, KCAT);
  k_gemm<EP_VT><<<dim3(8, 64, 1), dim3(256), 0, stream>>>(
      xcat, 0LL, KCAT, wt + 2 * 1024 * KCAT, 0LL, KCAT, vt, 0LL, 0, KCAT);

  // 3. scores S = Q K^T (split-bf16 3-term), fp32 out
  k_gemm<EP_F32><<<dim3(16, 16, 4), dim3(256), 0, stream>>>(
      qcat, (long long)2048 * KCAT, KCAT, kcat, (long long)2048 * KCAT, KCAT,
      Sbuf, (long long)2048 * 2048, 2048, KCAT);

  // 4. softmax in place (fp32 row -> bf16 row, lda becomes 4096 ushorts)
  k_softmax<<<dim3(8192), dim3(256), 0, stream>>>(Sbuf);

  // 5. O = P V  (plain bf16), fp32 out to d_out
  k_gemm<EP_F32><<<dim3(8, 16, 4), dim3(256), 0, stream>>>(
      (const ushort_t*)Sbuf, (long long)2048 * 4096, 4096,
      vt, (long long)1024 * 2048, 2048,
      out, (long long)2048 * 1024, 1024, 2048);
}

// Round 3
// 486.278 us; speedup vs baseline: 1.2457x; 1.1960x over previous
//
#include <hip/hip_runtime.h>
#include <cstdint>
#include <cstddef>

// B=4, S=2048, D=1024, U=1024 self-attention, fp32 in/out.
// R3: fp16 2-term split (KCAT=2048) for QKV + scores; fp16 for P,V.
//     GEMM tile 256x128, 4 waves x (128x64), mfma 16x16x32 f16,
//     global_load_lds width-16 staging + XOR bank swizzle.

typedef unsigned short ushort_t;
typedef _Float16 half_t;
typedef __attribute__((ext_vector_type(8))) short short8;
typedef __attribute__((ext_vector_type(4))) float floatx4;

__device__ inline unsigned short h2u(half_t h) {
  union { half_t h; unsigned short u; } v; v.h = h; return v.u;
}

// async 16B global -> LDS (DMA). LDS dest = wave-uniform base + lane*16 (HW).
__device__ __forceinline__ void gload16(const half_t* g, half_t* l) {
  __builtin_amdgcn_global_load_lds(
      (const __attribute__((address_space(1))) unsigned int*)g,
      (__attribute__((address_space(3))) unsigned int*)l, 16, 0, 0);
}

// ---------- constants ----------
#define MX 8192       // B*S
#define KCAT 2048     // 2*D (fp16 2-term split-concatenated K dim)

// ws byte offsets (regions reused across phases; S overwrites xcat/wt)
#define XCAT_OFF 0UL                  // half [8192][2048] = 33554432 B
#define WT_OFF   50331648UL           // half 3 x [1024][2048] = 12582912 B
#define S_OFF    0UL                  // float [4][2048][2048] = 67108864 B
#define QCAT_OFF 69206016UL           // half [8192][2048]
#define KCAT_OFF 119537664UL          // half [8192][2048]
#define VT_OFF   169869312UL          // half [4][1024][2048] = 16777216 B
#define WS_NEED  186646528UL

// ---------- K1a: split inputs X -> Xcat = [xh | xl] (fp16) ----------
__global__ __launch_bounds__(256) void k_split_x(const float* __restrict__ X,
                                                 half_t* __restrict__ xcat) {
  long long i = (long long)blockIdx.x * 256 + threadIdx.x;  // over 8192*1024
  float x = X[i];
  half_t h = (half_t)x;
  half_t lo = (half_t)(x - (float)h);
  long long row = i >> 10;
  int col = (int)(i & 1023);
  half_t* r = xcat + row * KCAT;
  r[col] = h;
  r[col + 1024] = lo;
}

// ---------- K1b: transpose W -> WT_cat = [Wh | Wh] per weight ----------
__global__ __launch_bounds__(256) void k_split_wt(const float* __restrict__ Wq,
                                                  const float* __restrict__ Wk,
                                                  const float* __restrict__ Wv,
                                                  half_t* __restrict__ wt) {
  __shared__ float tile[64][65];
  const float* W = (blockIdx.z == 0) ? Wq : ((blockIdx.z == 1) ? Wk : Wv);
  half_t* out = wt + (size_t)blockIdx.z * 1024 * KCAT;
  int d0 = blockIdx.y * 64, u0 = blockIdx.x * 64;
  int t = threadIdx.x;
  int tr = t >> 6, tc = t & 63;
  for (int r = 0; r < 64; r += 4)
    tile[r + tr][tc] = W[(size_t)(d0 + r + tr) * 1024 + (u0 + tc)];
  __syncthreads();
  for (int r = 0; r < 64; r += 4) {
    int urow = r + tr, dcol = tc;
    float x = tile[dcol][urow];  // = WT[u0+urow][d0+dcol]
    half_t h = (half_t)x;
    half_t* o = out + (size_t)(u0 + urow) * KCAT + d0;
    o[dcol] = h;
    o[dcol + 1024] = h;
  }
}

// ---------- GEMM: C[m][n] = sum_k A[m][k] * Bt[n][k] ----------
// 256x128 tile, 4 waves each 128x64 (8x4 frags of mfma_f32_16x16x32_f16), BK=32.
// LDS: As 256x32 half (1024 chunks of 16B), Bs 128x32 (512 chunks).
// Swizzle: LDS chunk (row,q) sourced from global chunk q ^ ((row>>1)&3).
enum { EP_F32 = 0, EP_QCAT = 1, EP_KCAT = 2, EP_VT = 3 };

template <int MODE>
__global__ __launch_bounds__(256, 2) void k_gemm(
    const half_t* __restrict__ A, long long aBatch, int lda,
    const half_t* __restrict__ Bt, long long bBatch, int ldb,
    void* __restrict__ Cout, long long cBatch, int ldc, int K) {
  __shared__ __align__(16) half_t As[256 * 32];
  __shared__ __align__(16) half_t Bs[128 * 32];
  const int t = threadIdx.x;
  const int z = blockIdx.z;
  A += (long long)z * aBatch;
  Bt += (long long)z * bBatch;
  const int m0 = blockIdx.y * 256, n0 = blockIdx.x * 128;

  const int w = t >> 6, l = t & 63;
  const int lr = l & 15, quad = l >> 4;
  const int wm = (w >> 1) * 128, wn = (w & 1) * 64;

  const floatx4 fz = {0.f, 0.f, 0.f, 0.f};
  floatx4 acc[8][4];
#pragma unroll
  for (int i = 0; i < 8; i++)
#pragma unroll
    for (int j = 0; j < 4; j++) acc[i][j] = fz;

  // staging: thread t covers chunks s*256+t; swizzled global column chunk
  const half_t* Ap[4];
  const half_t* Bp[2];
  half_t* ldsA[4];
  half_t* ldsB[2];
#pragma unroll
  for (int s = 0; s < 4; s++) {
    int c = s * 256 + t;
    Ap[s] = A + (long long)(m0 + (c >> 2)) * lda + (((c & 3) ^ ((c >> 3) & 3)) * 8);
    ldsA[s] = &As[(s * 256 + w * 64) * 8];
  }
#pragma unroll
  for (int s = 0; s < 2; s++) {
    int c = s * 256 + t;
    Bp[s] = Bt + (long long)(n0 + (c >> 2)) * ldb + (((c & 3) ^ ((c >> 3) & 3)) * 8);
    ldsB[s] = &Bs[(s * 256 + w * 64) * 8];
  }

  // fragment read offsets: chunk pos p = quad ^ ((lr>>1)&3) (row-independent,
  // since frag row bases are multiples of 16)
  const int p = quad ^ ((lr >> 1) & 3);
  const int aoff = (wm + lr) * 32 + p * 8;
  const int boff = (wn + lr) * 32 + p * 8;

  for (int kb = 0; kb < K; kb += 32) {
    __syncthreads();  // prior iter's frag reads done before overwrite
#pragma unroll
    for (int s = 0; s < 4; s++) gload16(Ap[s] + kb, ldsA[s]);
#pragma unroll
    for (int s = 0; s < 2; s++) gload16(Bp[s] + kb, ldsB[s]);
    __syncthreads();  // barrier drains vmcnt -> LDS data visible
    short8 af[8], bfg[4];
#pragma unroll
    for (int j = 0; j < 4; j++) bfg[j] = *(const short8*)&Bs[boff + j * 512];
#pragma unroll
    for (int i = 0; i < 8; i++) af[i] = *(const short8*)&As[aoff + i * 512];
#pragma unroll
    for (int i = 0; i < 8; i++)
#pragma unroll
      for (int j = 0; j < 4; j++)
        acc[i][j] = __builtin_amdgcn_mfma_f32_16x16x32_f16(af[i], bfg[j], acc[i][j], 0, 0, 0);
  }

  // epilogue: D[row = quad*4 + r][col = lr] per (i,j) subtile
#pragma unroll
  for (int i = 0; i < 8; i++) {
#pragma unroll
    for (int j = 0; j < 4; j++) {
#pragma unroll
      for (int r = 0; r < 4; r++) {
        int grow = m0 + wm + i * 16 + quad * 4 + r;
        int gcol = n0 + wn + j * 16 + lr;
        float v = acc[i][j][r];
        if (MODE == EP_F32) {
          float* C = (float*)Cout + (long long)z * cBatch;
          C[(long long)grow * ldc + gcol] = v;
        } else if (MODE == EP_QCAT || MODE == EP_KCAT) {
          half_t* pq = (half_t*)Cout + (long long)grow * KCAT;
          half_t h = (half_t)v;
          pq[gcol] = h;
          if (MODE == EP_QCAT)
            pq[gcol + 1024] = (half_t)(v - (float)h);  // Q = [qh | ql]
          else
            pq[gcol + 1024] = h;                       // K = [kh | kh]
        } else {  // EP_VT: V^T[b][u][s] = V[b*2048+s][u], fp16
          half_t* C = (half_t*)Cout;
          int b = grow >> 11, s = grow & 2047;
          C[((long long)b * 1024 + gcol) * 2048 + s] = (half_t)v;
        }
      }
    }
  }
}

// ---------- softmax, in place: S row (fp32[2048]) -> P row (fp16[2048]) ----------
__global__ __launch_bounds__(256) void k_softmax(float* __restrict__ Sbuf) {
  long long row = blockIdx.x;  // 0..8191
  float* p = Sbuf + row * 2048;
  int t = threadIdx.x;
  float4 v0 = ((const float4*)p)[t];
  float4 v1 = ((const float4*)p)[t + 256];
  float m = fmaxf(fmaxf(fmaxf(v0.x, v0.y), fmaxf(v0.z, v0.w)),
                  fmaxf(fmaxf(v1.x, v1.y), fmaxf(v1.z, v1.w)));
  for (int off = 32; off; off >>= 1) m = fmaxf(m, __shfl_xor(m, off));
  __shared__ float red[8];
  int wv = t >> 6, ln = t & 63;
  if (ln == 0) red[wv] = m;
  __syncthreads();
  m = fmaxf(fmaxf(red[0], red[1]), fmaxf(red[2], red[3]));
  float e0 = __expf(v0.x - m), e1 = __expf(v0.y - m), e2 = __expf(v0.z - m), e3 = __expf(v0.w - m);
  float e4 = __expf(v1.x - m), e5 = __expf(v1.y - m), e6 = __expf(v1.z - m), e7 = __expf(v1.w - m);
  float s = ((e0 + e1) + (e2 + e3)) + ((e4 + e5) + (e6 + e7));
  for (int off = 32; off; off >>= 1) s += __shfl_xor(s, off);
  if (ln == 0) red[4 + wv] = s;
  __syncthreads();
  s = (red[4] + red[5]) + (red[6] + red[7]);
  float inv = 1.0f / s;
  uint2 w0, w1;
  w0.x = (unsigned)h2u((half_t)(e0 * inv)) | ((unsigned)h2u((half_t)(e1 * inv)) << 16);
  w0.y = (unsigned)h2u((half_t)(e2 * inv)) | ((unsigned)h2u((half_t)(e3 * inv)) << 16);
  w1.x = (unsigned)h2u((half_t)(e4 * inv)) | ((unsigned)h2u((half_t)(e5 * inv)) << 16);
  w1.y = (unsigned)h2u((half_t)(e6 * inv)) | ((unsigned)h2u((half_t)(e7 * inv)) << 16);
  ((uint2*)p)[t] = w0;         // fp16 elements 4t .. 4t+3
  ((uint2*)p)[t + 256] = w1;   // fp16 elements 1024+4t ..
}

// ---------- host launch ----------
extern "C" void kernel_launch(void* const* d_in, const int* in_sizes, int n_in,
                              void* d_out, int out_size, void* d_ws, size_t ws_size,
                              hipStream_t stream) {
  (void)in_sizes; (void)n_in; (void)out_size;
  if (ws_size < WS_NEED) return;  // output stays poisoned -> visible failure

  const float* X = (const float*)d_in[0];
  const float* Wq = (const float*)d_in[1];
  const float* Wk = (const float*)d_in[2];
  const float* Wv = (const float*)d_in[3];
  char* ws = (char*)d_ws;
  half_t* xcat = (half_t*)(ws + XCAT_OFF);
  half_t* wt = (half_t*)(ws + WT_OFF);
  float* Sbuf = (float*)(ws + S_OFF);
  half_t* qcat = (half_t*)(ws + QCAT_OFF);
  half_t* kcat = (half_t*)(ws + KCAT_OFF);
  half_t* vt = (half_t*)(ws + VT_OFF);
  float* out = (float*)d_out;

  // 1. split X and W (fp16)
  k_split_x<<<dim3(MX * 1024 / 256), dim3(256), 0, stream>>>(X, xcat);
  k_split_wt<<<dim3(16, 16, 3), dim3(256), 0, stream>>>(Wq, Wk, Wv, wt);

  // 2. QKV projections (fp16 2-term via K=2048 cat): M=8192, N=1024
  k_gemm<EP_QCAT><<<dim3(8, 32, 1), dim3(256), 0, stream>>>(
      xcat, 0LL, KCAT, wt, 0LL, KCAT, qcat, 0LL, 0, KCAT);
  k_gemm<EP_KCAT><<<dim3(8, 32, 1), dim3(256), 0, stream>>>(
      xcat, 0LL, KCAT, wt + 1024 * KCAT, 0LL, KCAT, kcat, 0LL, 0, KCAT);
  k_gemm<EP_VT><<<dim3(8, 32, 1), dim3(256), 0, stream>>>(
      xcat, 0LL, KCAT, wt + 2 * 1024 * KCAT, 0LL, KCAT, vt, 0LL, 0, KCAT);

  // 3. scores S = Q K^T (fp16 2-term), fp32 out: per batch M=N=2048
  k_gemm<EP_F32><<<dim3(16, 8, 4), dim3(256), 0, stream>>>(
      qcat, (long long)2048 * KCAT, KCAT, kcat, (long long)2048 * KCAT, KCAT,
      Sbuf, (long long)2048 * 2048, 2048, KCAT);

  // 4. softmax in place (fp32 row -> fp16 row; row stride becomes 4096 halves)
  k_softmax<<<dim3(8192), dim3(256), 0, stream>>>(Sbuf);

  // 5. O = P V (plain fp16), fp32 out: per batch M=2048, N=1024, K=2048
  k_gemm<EP_F32><<<dim3(8, 8, 4), dim3(256), 0, stream>>>(
      (const half_t*)Sbuf, (long long)2048 * 4096, 4096,
      vt, (long long)1024 * 2048, 2048,
      out, (long long)2048 * 1024, 1024, 2048);
}

// Round 4
// 432.385 us; speedup vs baseline: 1.4009x; 1.1246x over previous
//
#include <hip/hip_runtime.h>
#include <cstdint>
#include <cstddef>

// B=4, S=2048, D=1024, U=1024 self-attention, fp32 in/out.
// R4: double-buffered LDS prefetch (post-barrier issue) + fused QKV GEMM (N=3072).
//     fp16 2-term split (KCAT=2048) for QKV + scores; fp16 for P,V.
//     GEMM tile 256x128, 4 waves x (128x64), mfma 16x16x32 f16,
//     global_load_lds width-16 staging + XOR bank swizzle.

typedef unsigned short ushort_t;
typedef _Float16 half_t;
typedef __attribute__((ext_vector_type(8))) short short8;
typedef __attribute__((ext_vector_type(4))) float floatx4;

__device__ inline unsigned short h2u(half_t h) {
  union { half_t h; unsigned short u; } v; v.h = h; return v.u;
}

// async 16B global -> LDS (DMA). LDS dest = wave-uniform base + lane*16 (HW).
__device__ __forceinline__ void gload16(const half_t* g, half_t* l) {
  __builtin_amdgcn_global_load_lds(
      (const __attribute__((address_space(1))) unsigned int*)g,
      (__attribute__((address_space(3))) unsigned int*)l, 16, 0, 0);
}

// ---------- constants ----------
#define MX 8192       // B*S
#define KCAT 2048     // 2*D (fp16 2-term split-concatenated K dim)

// ws byte offsets (regions reused across phases; S overwrites xcat/wt)
#define XCAT_OFF 0UL                  // half [8192][2048] = 33554432 B
#define WT_OFF   50331648UL           // half 3 x [1024][2048] = 12582912 B
#define S_OFF    0UL                  // float [4][2048][2048] = 67108864 B
#define QCAT_OFF 69206016UL           // half [8192][2048]
#define KCAT_OFF 119537664UL          // half [8192][2048]
#define VT_OFF   169869312UL          // half [4][1024][2048] = 16777216 B
#define WS_NEED  186646528UL

// ---------- K1a: split inputs X -> Xcat = [xh | xl] (fp16) ----------
__global__ __launch_bounds__(256) void k_split_x(const float* __restrict__ X,
                                                 half_t* __restrict__ xcat) {
  long long i = (long long)blockIdx.x * 256 + threadIdx.x;  // over 8192*1024
  float x = X[i];
  half_t h = (half_t)x;
  half_t lo = (half_t)(x - (float)h);
  long long row = i >> 10;
  int col = (int)(i & 1023);
  half_t* r = xcat + row * KCAT;
  r[col] = h;
  r[col + 1024] = lo;
}

// ---------- K1b: transpose W -> WT_cat = [Wh | Wh] per weight ----------
__global__ __launch_bounds__(256) void k_split_wt(const float* __restrict__ Wq,
                                                  const float* __restrict__ Wk,
                                                  const float* __restrict__ Wv,
                                                  half_t* __restrict__ wt) {
  __shared__ float tile[64][65];
  const float* W = (blockIdx.z == 0) ? Wq : ((blockIdx.z == 1) ? Wk : Wv);
  half_t* out = wt + (size_t)blockIdx.z * 1024 * KCAT;
  int d0 = blockIdx.y * 64, u0 = blockIdx.x * 64;
  int t = threadIdx.x;
  int tr = t >> 6, tc = t & 63;
  for (int r = 0; r < 64; r += 4)
    tile[r + tr][tc] = W[(size_t)(d0 + r + tr) * 1024 + (u0 + tc)];
  __syncthreads();
  for (int r = 0; r < 64; r += 4) {
    int urow = r + tr, dcol = tc;
    float x = tile[dcol][urow];  // = WT[u0+urow][d0+dcol]
    half_t h = (half_t)x;
    half_t* o = out + (size_t)(u0 + urow) * KCAT + d0;
    o[dcol] = h;
    o[dcol + 1024] = h;
  }
}

// ---------- GEMM: C[m][n] = sum_k A[m][k] * Bt[n][k] ----------
// 256x128 tile, 4 waves each 128x64 (8x4 frags of mfma_f32_16x16x32_f16), BK=32.
// Double-buffered LDS; prefetch for iter k+1 issued AFTER iter k's barrier so the
// compiler's vmcnt(0)-at-barrier only hits loads that aged a full compute phase.
// Swizzle: LDS chunk (row,q) sourced from global chunk q ^ ((row>>1)&3).
enum { EP_F32 = 0, EP_QKV = 1 };
#define ABUF (256 * 32)
#define BBUF (128 * 32)

template <int MODE>
__global__ __launch_bounds__(256, 2) void k_gemm(
    const half_t* __restrict__ A, long long aBatch, int lda,
    const half_t* __restrict__ Bt, long long bBatch, int ldb,
    void* __restrict__ Cout, long long cBatch, int ldc, int K,
    half_t* __restrict__ CoutK, half_t* __restrict__ CoutV) {
  __shared__ __align__(16) half_t As[2 * ABUF];
  __shared__ __align__(16) half_t Bs[2 * BBUF];
  const int t = threadIdx.x;
  const int z = blockIdx.z;
  A += (long long)z * aBatch;
  Bt += (long long)z * bBatch;
  const int m0 = blockIdx.y * 256, n0 = blockIdx.x * 128;

  const int w = t >> 6, l = t & 63;
  const int lr = l & 15, quad = l >> 4;
  const int wm = (w >> 1) * 128, wn = (w & 1) * 64;

  const floatx4 fz = {0.f, 0.f, 0.f, 0.f};
  floatx4 acc[8][4];
#pragma unroll
  for (int i = 0; i < 8; i++)
#pragma unroll
    for (int j = 0; j < 4; j++) acc[i][j] = fz;

  // staging: thread t covers chunks s*256+t; swizzled global column chunk
  const half_t* Ap[4];
  const half_t* Bp[2];
  half_t* ldsA[4];
  half_t* ldsB[2];
#pragma unroll
  for (int s = 0; s < 4; s++) {
    int c = s * 256 + t;
    Ap[s] = A + (long long)(m0 + (c >> 2)) * lda + (((c & 3) ^ ((c >> 3) & 3)) * 8);
    ldsA[s] = &As[(s * 256 + w * 64) * 8];
  }
#pragma unroll
  for (int s = 0; s < 2; s++) {
    int c = s * 256 + t;
    Bp[s] = Bt + (long long)(n0 + (c >> 2)) * ldb + (((c & 3) ^ ((c >> 3) & 3)) * 8);
    ldsB[s] = &Bs[(s * 256 + w * 64) * 8];
  }

  // fragment read offsets: chunk pos p = quad ^ ((lr>>1)&3)
  const int p = quad ^ ((lr >> 1) & 3);
  const int aoff = (wm + lr) * 32 + p * 8;
  const int boff = (wn + lr) * 32 + p * 8;

  // prologue: stage tile 0 into buffer 0
#pragma unroll
  for (int s = 0; s < 4; s++) gload16(Ap[s], ldsA[s]);
#pragma unroll
  for (int s = 0; s < 2; s++) gload16(Bp[s], ldsB[s]);

  int buf = 0;
  for (int kb = 0; kb < K; kb += 32, buf ^= 1) {
    __syncthreads();  // drains vmcnt -> buf's tile visible; prev compute done
    int kn = kb + 32;
    if (kn < K) {     // prefetch next tile into other buffer (post-barrier!)
      int nb = buf ^ 1;
#pragma unroll
      for (int s = 0; s < 4; s++) gload16(Ap[s] + kn, ldsA[s] + nb * ABUF);
#pragma unroll
      for (int s = 0; s < 2; s++) gload16(Bp[s] + kn, ldsB[s] + nb * BBUF);
    }
    const half_t* as = &As[buf * ABUF];
    const half_t* bs = &Bs[buf * BBUF];
    short8 af[8], bfg[4];
#pragma unroll
    for (int j = 0; j < 4; j++) bfg[j] = *(const short8*)&bs[boff + j * 512];
#pragma unroll
    for (int i = 0; i < 8; i++) af[i] = *(const short8*)&as[aoff + i * 512];
#pragma unroll
    for (int i = 0; i < 8; i++)
#pragma unroll
      for (int j = 0; j < 4; j++)
        acc[i][j] = __builtin_amdgcn_mfma_f32_16x16x32_f16(af[i], bfg[j], acc[i][j], 0, 0, 0);
  }

  // epilogue: D[row = quad*4 + r][col = lr] per (i,j) subtile
#pragma unroll
  for (int i = 0; i < 8; i++) {
#pragma unroll
    for (int j = 0; j < 4; j++) {
#pragma unroll
      for (int r = 0; r < 4; r++) {
        int grow = m0 + wm + i * 16 + quad * 4 + r;
        int gcol = n0 + wn + j * 16 + lr;
        float v = acc[i][j][r];
        if (MODE == EP_F32) {
          float* C = (float*)Cout + (long long)z * cBatch;
          C[(long long)grow * ldc + gcol] = v;
        } else {  // EP_QKV: gcol in [0,3072); sel uniform per (block,j)
          int sel = gcol >> 10;
          int ucol = gcol & 1023;
          half_t h = (half_t)v;
          if (sel == 0) {        // Q = [qh | ql]
            half_t* pq = (half_t*)Cout + (long long)grow * KCAT;
            pq[ucol] = h;
            pq[ucol + 1024] = (half_t)(v - (float)h);
          } else if (sel == 1) { // K = [kh | kh]
            half_t* pk = CoutK + (long long)grow * KCAT;
            pk[ucol] = h;
            pk[ucol + 1024] = h;
          } else {               // V^T[b][u][s] = V[b*2048+s][u]
            int b = grow >> 11, s = grow & 2047;
            CoutV[((long long)b * 1024 + ucol) * 2048 + s] = h;
          }
        }
      }
    }
  }
}

// ---------- softmax, in place: S row (fp32[2048]) -> P row (fp16[2048]) ----------
__global__ __launch_bounds__(256) void k_softmax(float* __restrict__ Sbuf) {
  long long row = blockIdx.x;  // 0..8191
  float* p = Sbuf + row * 2048;
  int t = threadIdx.x;
  float4 v0 = ((const float4*)p)[t];
  float4 v1 = ((const float4*)p)[t + 256];
  float m = fmaxf(fmaxf(fmaxf(v0.x, v0.y), fmaxf(v0.z, v0.w)),
                  fmaxf(fmaxf(v1.x, v1.y), fmaxf(v1.z, v1.w)));
  for (int off = 32; off; off >>= 1) m = fmaxf(m, __shfl_xor(m, off));
  __shared__ float red[8];
  int wv = t >> 6, ln = t & 63;
  if (ln == 0) red[wv] = m;
  __syncthreads();
  m = fmaxf(fmaxf(red[0], red[1]), fmaxf(red[2], red[3]));
  float e0 = __expf(v0.x - m), e1 = __expf(v0.y - m), e2 = __expf(v0.z - m), e3 = __expf(v0.w - m);
  float e4 = __expf(v1.x - m), e5 = __expf(v1.y - m), e6 = __expf(v1.z - m), e7 = __expf(v1.w - m);
  float s = ((e0 + e1) + (e2 + e3)) + ((e4 + e5) + (e6 + e7));
  for (int off = 32; off; off >>= 1) s += __shfl_xor(s, off);
  if (ln == 0) red[4 + wv] = s;
  __syncthreads();
  s = (red[4] + red[5]) + (red[6] + red[7]);
  float inv = 1.0f / s;
  uint2 w0, w1;
  w0.x = (unsigned)h2u((half_t)(e0 * inv)) | ((unsigned)h2u((half_t)(e1 * inv)) << 16);
  w0.y = (unsigned)h2u((half_t)(e2 * inv)) | ((unsigned)h2u((half_t)(e3 * inv)) << 16);
  w1.x = (unsigned)h2u((half_t)(e4 * inv)) | ((unsigned)h2u((half_t)(e5 * inv)) << 16);
  w1.y = (unsigned)h2u((half_t)(e6 * inv)) | ((unsigned)h2u((half_t)(e7 * inv)) << 16);
  ((uint2*)p)[t] = w0;         // fp16 elements 4t .. 4t+3
  ((uint2*)p)[t + 256] = w1;   // fp16 elements 1024+4t ..
}

// ---------- host launch ----------
extern "C" void kernel_launch(void* const* d_in, const int* in_sizes, int n_in,
                              void* d_out, int out_size, void* d_ws, size_t ws_size,
                              hipStream_t stream) {
  (void)in_sizes; (void)n_in; (void)out_size;
  if (ws_size < WS_NEED) return;  // output stays poisoned -> visible failure

  const float* X = (const float*)d_in[0];
  const float* Wq = (const float*)d_in[1];
  const float* Wk = (const float*)d_in[2];
  const float* Wv = (const float*)d_in[3];
  char* ws = (char*)d_ws;
  half_t* xcat = (half_t*)(ws + XCAT_OFF);
  half_t* wt = (half_t*)(ws + WT_OFF);
  float* Sbuf = (float*)(ws + S_OFF);
  half_t* qcat = (half_t*)(ws + QCAT_OFF);
  half_t* kcat = (half_t*)(ws + KCAT_OFF);
  half_t* vt = (half_t*)(ws + VT_OFF);
  float* out = (float*)d_out;

  // 1. split X and W (fp16)
  k_split_x<<<dim3(MX * 1024 / 256), dim3(256), 0, stream>>>(X, xcat);
  k_split_wt<<<dim3(16, 16, 3), dim3(256), 0, stream>>>(Wq, Wk, Wv, wt);

  // 2. fused QKV projection: M=8192, N=3072 (Q|K|V), K=2048 -> 768 blocks
  k_gemm<EP_QKV><<<dim3(24, 32, 1), dim3(256), 0, stream>>>(
      xcat, 0LL, KCAT, wt, 0LL, KCAT, qcat, 0LL, 0, KCAT, kcat, vt);

  // 3. scores S = Q K^T (fp16 2-term), fp32 out: per batch M=N=2048
  k_gemm<EP_F32><<<dim3(16, 8, 4), dim3(256), 0, stream>>>(
      qcat, (long long)2048 * KCAT, KCAT, kcat, (long long)2048 * KCAT, KCAT,
      Sbuf, (long long)2048 * 2048, 2048, KCAT, nullptr, nullptr);

  // 4. softmax in place (fp32 row -> fp16 row; row stride becomes 4096 halves)
  k_softmax<<<dim3(8192), dim3(256), 0, stream>>>(Sbuf);

  // 5. O = P V (plain fp16), fp32 out: per batch M=2048, N=1024, K=2048
  k_gemm<EP_F32><<<dim3(8, 8, 4), dim3(256), 0, stream>>>(
      (const half_t*)Sbuf, (long long)2048 * 4096, 4096,
      vt, (long long)1024 * 2048, 2048,
      out, (long long)2048 * 1024, 1024, 2048, nullptr, nullptr);
}

// Round 6
// 415.075 us; speedup vs baseline: 1.4593x; 1.0417x over previous
//
#include <hip/hip_runtime.h>
#include <cstdint>
#include <cstddef>

// B=4, S=2048, D=1024, U=1024 self-attention, fp32 in/out.
// R6: R5 (128x128 tile, 4 blocks/CU, dbuf prefetch) with staging fix:
//     512 chunks/tile = 2 chunks per thread (R5 loaded only 256 -> NaN).
//     fp16 2-term split (KCAT=2048) for QKV + scores; fp16 for P,V.

typedef unsigned short ushort_t;
typedef _Float16 half_t;
typedef __attribute__((ext_vector_type(8))) short short8;
typedef __attribute__((ext_vector_type(4))) float floatx4;

__device__ inline unsigned short h2u(half_t h) {
  union { half_t h; unsigned short u; } v; v.h = h; return v.u;
}

// async 16B global -> LDS (DMA). LDS dest = wave-uniform base + lane*16 (HW).
__device__ __forceinline__ void gload16(const half_t* g, half_t* l) {
  __builtin_amdgcn_global_load_lds(
      (const __attribute__((address_space(1))) unsigned int*)g,
      (__attribute__((address_space(3))) unsigned int*)l, 16, 0, 0);
}

// ---------- constants ----------
#define MX 8192       // B*S
#define KCAT 2048     // 2*D (fp16 2-term split-concatenated K dim)

// ws byte offsets (regions reused across phases; S overwrites xcat/wt)
#define XCAT_OFF 0UL                  // half [8192][2048] = 33554432 B
#define WT_OFF   50331648UL           // half 3 x [1024][2048] = 12582912 B
#define S_OFF    0UL                  // float [4][2048][2048] = 67108864 B
#define QCAT_OFF 69206016UL           // half [8192][2048]
#define KCAT_OFF 119537664UL          // half [8192][2048]
#define VT_OFF   169869312UL          // half [4][1024][2048] = 16777216 B
#define WS_NEED  186646528UL

// ---------- K1a: split inputs X -> Xcat = [xh | xl] (fp16) ----------
__global__ __launch_bounds__(256) void k_split_x(const float* __restrict__ X,
                                                 half_t* __restrict__ xcat) {
  long long i = (long long)blockIdx.x * 256 + threadIdx.x;  // over 8192*1024
  float x = X[i];
  half_t h = (half_t)x;
  half_t lo = (half_t)(x - (float)h);
  long long row = i >> 10;
  int col = (int)(i & 1023);
  half_t* r = xcat + row * KCAT;
  r[col] = h;
  r[col + 1024] = lo;
}

// ---------- K1b: transpose W -> WT_cat = [Wh | Wh] per weight ----------
__global__ __launch_bounds__(256) void k_split_wt(const float* __restrict__ Wq,
                                                  const float* __restrict__ Wk,
                                                  const float* __restrict__ Wv,
                                                  half_t* __restrict__ wt) {
  __shared__ float tile[64][65];
  const float* W = (blockIdx.z == 0) ? Wq : ((blockIdx.z == 1) ? Wk : Wv);
  half_t* out = wt + (size_t)blockIdx.z * 1024 * KCAT;
  int d0 = blockIdx.y * 64, u0 = blockIdx.x * 64;
  int t = threadIdx.x;
  int tr = t >> 6, tc = t & 63;
  for (int r = 0; r < 64; r += 4)
    tile[r + tr][tc] = W[(size_t)(d0 + r + tr) * 1024 + (u0 + tc)];
  __syncthreads();
  for (int r = 0; r < 64; r += 4) {
    int urow = r + tr, dcol = tc;
    float x = tile[dcol][urow];  // = WT[u0+urow][d0+dcol]
    half_t h = (half_t)x;
    half_t* o = out + (size_t)(u0 + urow) * KCAT + d0;
    o[dcol] = h;
    o[dcol + 1024] = h;
  }
}

// ---------- GEMM: C[m][n] = sum_k A[m][k] * Bt[n][k] ----------
// 128x128 tile, 4 waves each 64x64 (4x4 frags of mfma_f32_16x16x32_f16), BK=32.
// Double-buffered LDS; prefetch for iter k+1 issued AFTER iter k's barrier.
// Tile = 512 chunks of 16B: thread t stages chunks t and t+256.
// Swizzle: LDS chunk (row,q) sourced from global chunk q ^ ((row>>1)&3).
enum { EP_F32 = 0, EP_QKV = 1 };
#define TBUF (128 * 32)   // halves per LDS tile buffer (8 KB)

template <int MODE>
__global__ __launch_bounds__(256, 4) void k_gemm(
    const half_t* __restrict__ A, long long aBatch, int lda,
    const half_t* __restrict__ Bt, long long bBatch, int ldb,
    void* __restrict__ Cout, long long cBatch, int ldc, int K,
    half_t* __restrict__ CoutK, half_t* __restrict__ CoutV) {
  __shared__ __align__(16) half_t As[2 * TBUF];
  __shared__ __align__(16) half_t Bs[2 * TBUF];
  const int t = threadIdx.x;
  const int z = blockIdx.z;
  A += (long long)z * aBatch;
  Bt += (long long)z * bBatch;
  const int m0 = blockIdx.y * 128, n0 = blockIdx.x * 128;

  const int w = t >> 6, l = t & 63;
  const int lr = l & 15, quad = l >> 4;
  const int wm = (w >> 1) * 64, wn = (w & 1) * 64;

  const floatx4 fz = {0.f, 0.f, 0.f, 0.f};
  floatx4 acc[4][4];
#pragma unroll
  for (int i = 0; i < 4; i++)
#pragma unroll
    for (int j = 0; j < 4; j++) acc[i][j] = fz;

  // staging: 512 chunks of 16B per matrix tile; thread t handles chunks t and
  // t+256, with swizzled global column chunk.
  const int c0 = t, c1 = t + 256;
  const half_t* Ap0 = A + (long long)(m0 + (c0 >> 2)) * lda + (((c0 & 3) ^ ((c0 >> 3) & 3)) * 8);
  const half_t* Ap1 = A + (long long)(m0 + (c1 >> 2)) * lda + (((c1 & 3) ^ ((c1 >> 3) & 3)) * 8);
  const half_t* Bp0 = Bt + (long long)(n0 + (c0 >> 2)) * ldb + (((c0 & 3) ^ ((c0 >> 3) & 3)) * 8);
  const half_t* Bp1 = Bt + (long long)(n0 + (c1 >> 2)) * ldb + (((c1 & 3) ^ ((c1 >> 3) & 3)) * 8);
  // wave-uniform LDS bases; lane adds l*16B in HW
  half_t* ldsA0 = &As[(w * 64) * 8];
  half_t* ldsA1 = &As[(256 + w * 64) * 8];
  half_t* ldsB0 = &Bs[(w * 64) * 8];
  half_t* ldsB1 = &Bs[(256 + w * 64) * 8];

  // fragment read offsets: chunk pos p = quad ^ ((lr>>1)&3)
  const int p = quad ^ ((lr >> 1) & 3);
  const int aoff = (wm + lr) * 32 + p * 8;
  const int boff = (wn + lr) * 32 + p * 8;

  // prologue: stage tile 0 into buffer 0
  gload16(Ap0, ldsA0);
  gload16(Ap1, ldsA1);
  gload16(Bp0, ldsB0);
  gload16(Bp1, ldsB1);

  int buf = 0;
  for (int kb = 0; kb < K; kb += 32, buf ^= 1) {
    __syncthreads();  // drains vmcnt -> buf's tile visible; prev compute done
    int kn = kb + 32;
    if (kn < K) {     // prefetch next tile into other buffer (post-barrier!)
      int nb = buf ^ 1;
      gload16(Ap0 + kn, ldsA0 + nb * TBUF);
      gload16(Ap1 + kn, ldsA1 + nb * TBUF);
      gload16(Bp0 + kn, ldsB0 + nb * TBUF);
      gload16(Bp1 + kn, ldsB1 + nb * TBUF);
    }
    const half_t* as = &As[buf * TBUF];
    const half_t* bs = &Bs[buf * TBUF];
    short8 af[4], bfg[4];
#pragma unroll
    for (int j = 0; j < 4; j++) bfg[j] = *(const short8*)&bs[boff + j * 512];
#pragma unroll
    for (int i = 0; i < 4; i++) af[i] = *(const short8*)&as[aoff + i * 512];
#pragma unroll
    for (int i = 0; i < 4; i++)
#pragma unroll
      for (int j = 0; j < 4; j++)
        acc[i][j] = __builtin_amdgcn_mfma_f32_16x16x32_f16(af[i], bfg[j], acc[i][j], 0, 0, 0);
  }

  // epilogue: D[row = quad*4 + r][col = lr] per (i,j) subtile
#pragma unroll
  for (int i = 0; i < 4; i++) {
#pragma unroll
    for (int j = 0; j < 4; j++) {
#pragma unroll
      for (int r = 0; r < 4; r++) {
        int grow = m0 + wm + i * 16 + quad * 4 + r;
        int gcol = n0 + wn + j * 16 + lr;
        float v = acc[i][j][r];
        if (MODE == EP_F32) {
          float* C = (float*)Cout + (long long)z * cBatch;
          C[(long long)grow * ldc + gcol] = v;
        } else {  // EP_QKV: gcol in [0,3072); sel uniform per (block,j)
          int sel = gcol >> 10;
          int ucol = gcol & 1023;
          half_t h = (half_t)v;
          if (sel == 0) {        // Q = [qh | ql]
            half_t* pq = (half_t*)Cout + (long long)grow * KCAT;
            pq[ucol] = h;
            pq[ucol + 1024] = (half_t)(v - (float)h);
          } else if (sel == 1) { // K = [kh | kh]
            half_t* pk = CoutK + (long long)grow * KCAT;
            pk[ucol] = h;
            pk[ucol + 1024] = h;
          } else {               // V^T[b][u][s] = V[b*2048+s][u]
            int b = grow >> 11, s = grow & 2047;
            CoutV[((long long)b * 1024 + ucol) * 2048 + s] = h;
          }
        }
      }
    }
  }
}

// ---------- softmax, in place: S row (fp32[2048]) -> P row (fp16[2048]) ----------
__global__ __launch_bounds__(256) void k_softmax(float* __restrict__ Sbuf) {
  long long row = blockIdx.x;  // 0..8191
  float* p = Sbuf + row * 2048;
  int t = threadIdx.x;
  float4 v0 = ((const float4*)p)[t];
  float4 v1 = ((const float4*)p)[t + 256];
  float m = fmaxf(fmaxf(fmaxf(v0.x, v0.y), fmaxf(v0.z, v0.w)),
                  fmaxf(fmaxf(v1.x, v1.y), fmaxf(v1.z, v1.w)));
  for (int off = 32; off; off >>= 1) m = fmaxf(m, __shfl_xor(m, off));
  __shared__ float red[8];
  int wv = t >> 6, ln = t & 63;
  if (ln == 0) red[wv] = m;
  __syncthreads();
  m = fmaxf(fmaxf(red[0], red[1]), fmaxf(red[2], red[3]));
  float e0 = __expf(v0.x - m), e1 = __expf(v0.y - m), e2 = __expf(v0.z - m), e3 = __expf(v0.w - m);
  float e4 = __expf(v1.x - m), e5 = __expf(v1.y - m), e6 = __expf(v1.z - m), e7 = __expf(v1.w - m);
  float s = ((e0 + e1) + (e2 + e3)) + ((e4 + e5) + (e6 + e7));
  for (int off = 32; off; off >>= 1) s += __shfl_xor(s, off);
  if (ln == 0) red[4 + wv] = s;
  __syncthreads();
  s = (red[4] + red[5]) + (red[6] + red[7]);
  float inv = 1.0f / s;
  uint2 w0, w1;
  w0.x = (unsigned)h2u((half_t)(e0 * inv)) | ((unsigned)h2u((half_t)(e1 * inv)) << 16);
  w0.y = (unsigned)h2u((half_t)(e2 * inv)) | ((unsigned)h2u((half_t)(e3 * inv)) << 16);
  w1.x = (unsigned)h2u((half_t)(e4 * inv)) | ((unsigned)h2u((half_t)(e5 * inv)) << 16);
  w1.y = (unsigned)h2u((half_t)(e6 * inv)) | ((unsigned)h2u((half_t)(e7 * inv)) << 16);
  ((uint2*)p)[t] = w0;         // fp16 elements 4t .. 4t+3
  ((uint2*)p)[t + 256] = w1;   // fp16 elements 1024+4t ..
}

// ---------- host launch ----------
extern "C" void kernel_launch(void* const* d_in, const int* in_sizes, int n_in,
                              void* d_out, int out_size, void* d_ws, size_t ws_size,
                              hipStream_t stream) {
  (void)in_sizes; (void)n_in; (void)out_size;
  if (ws_size < WS_NEED) return;  // output stays poisoned -> visible failure

  const float* X = (const float*)d_in[0];
  const float* Wq = (const float*)d_in[1];
  const float* Wk = (const float*)d_in[2];
  const float* Wv = (const float*)d_in[3];
  char* ws = (char*)d_ws;
  half_t* xcat = (half_t*)(ws + XCAT_OFF);
  half_t* wt = (half_t*)(ws + WT_OFF);
  float* Sbuf = (float*)(ws + S_OFF);
  half_t* qcat = (half_t*)(ws + QCAT_OFF);
  half_t* kcat = (half_t*)(ws + KCAT_OFF);
  half_t* vt = (half_t*)(ws + VT_OFF);
  float* out = (float*)d_out;

  // 1. split X and W (fp16)
  k_split_x<<<dim3(MX * 1024 / 256), dim3(256), 0, stream>>>(X, xcat);
  k_split_wt<<<dim3(16, 16, 3), dim3(256), 0, stream>>>(Wq, Wk, Wv, wt);

  // 2. fused QKV projection: M=8192, N=3072 (Q|K|V), K=2048 -> 1536 blocks
  k_gemm<EP_QKV><<<dim3(24, 64, 1), dim3(256), 0, stream>>>(
      xcat, 0LL, KCAT, wt, 0LL, KCAT, qcat, 0LL, 0, KCAT, kcat, vt);

  // 3. scores S = Q K^T (fp16 2-term), fp32 out: per batch M=N=2048
  k_gemm<EP_F32><<<dim3(16, 16, 4), dim3(256), 0, stream>>>(
      qcat, (long long)2048 * KCAT, KCAT, kcat, (long long)2048 * KCAT, KCAT,
      Sbuf, (long long)2048 * 2048, 2048, KCAT, nullptr, nullptr);

  // 4. softmax in place (fp32 row -> fp16 row; row stride becomes 4096 halves)
  k_softmax<<<dim3(8192), dim3(256), 0, stream>>>(Sbuf);

  // 5. O = P V (plain fp16), fp32 out: per batch M=2048, N=1024, K=2048
  k_gemm<EP_F32><<<dim3(8, 16, 4), dim3(256), 0, stream>>>(
      (const half_t*)Sbuf, (long long)2048 * 4096, 4096,
      vt, (long long)1024 * 2048, 2048,
      out, (long long)2048 * 1024, 1024, 2048, nullptr, nullptr);
}

// Round 7
// 335.711 us; speedup vs baseline: 1.8043x; 1.2364x over previous
//
#include <hip/hip_runtime.h>
#include <cstdint>
#include <cstddef>

// B=4, S=2048, D=1024, U=1024 self-attention, fp32 in/out.
// R7: BK=64 single-buffered (2-barrier) GEMM core, 128x128 tile, 4 blocks/CU,
//     8-way XOR swizzle, global_load_lds staging. V projection split off at
//     K=1024 1-term. fp16 2-term split (KCAT=2048) for QK-proj + scores.

typedef unsigned short ushort_t;
typedef _Float16 half_t;
typedef __attribute__((ext_vector_type(8))) short short8;
typedef __attribute__((ext_vector_type(4))) float floatx4;

__device__ inline unsigned short h2u(half_t h) {
  union { half_t h; unsigned short u; } v; v.h = h; return v.u;
}

// async 16B global -> LDS (DMA). LDS dest = wave-uniform base + lane*16 (HW).
__device__ __forceinline__ void gload16(const half_t* g, half_t* l) {
  __builtin_amdgcn_global_load_lds(
      (const __attribute__((address_space(1))) unsigned int*)g,
      (__attribute__((address_space(3))) unsigned int*)l, 16, 0, 0);
}

// ---------- constants ----------
#define MX 8192       // B*S
#define KCAT 2048     // 2*D (fp16 2-term split-concatenated K dim)

// ws byte offsets (regions reused across phases; S overwrites xcat/wt)
#define XCAT_OFF 0UL                  // half [8192][2048] = 33554432 B
#define WT_OFF   50331648UL           // half 3 x [1024][2048] = 12582912 B
#define S_OFF    0UL                  // float [4][2048][2048] = 67108864 B
#define QCAT_OFF 69206016UL           // half [8192][2048]
#define KCAT_OFF 119537664UL          // half [8192][2048]
#define VT_OFF   169869312UL          // half [4][1024][2048] = 16777216 B
#define WS_NEED  186646528UL

// ---------- K1a: split inputs X -> Xcat = [xh | xl] (fp16) ----------
__global__ __launch_bounds__(256) void k_split_x(const float* __restrict__ X,
                                                 half_t* __restrict__ xcat) {
  long long i = (long long)blockIdx.x * 256 + threadIdx.x;  // over 8192*1024
  float x = X[i];
  half_t h = (half_t)x;
  half_t lo = (half_t)(x - (float)h);
  long long row = i >> 10;
  int col = (int)(i & 1023);
  half_t* r = xcat + row * KCAT;
  r[col] = h;
  r[col + 1024] = lo;
}

// ---------- K1b: transpose W -> WT_cat = [Wh | Wh] per weight ----------
__global__ __launch_bounds__(256) void k_split_wt(const float* __restrict__ Wq,
                                                  const float* __restrict__ Wk,
                                                  const float* __restrict__ Wv,
                                                  half_t* __restrict__ wt) {
  __shared__ float tile[64][65];
  const float* W = (blockIdx.z == 0) ? Wq : ((blockIdx.z == 1) ? Wk : Wv);
  half_t* out = wt + (size_t)blockIdx.z * 1024 * KCAT;
  int d0 = blockIdx.y * 64, u0 = blockIdx.x * 64;
  int t = threadIdx.x;
  int tr = t >> 6, tc = t & 63;
  for (int r = 0; r < 64; r += 4)
    tile[r + tr][tc] = W[(size_t)(d0 + r + tr) * 1024 + (u0 + tc)];
  __syncthreads();
  for (int r = 0; r < 64; r += 4) {
    int urow = r + tr, dcol = tc;
    float x = tile[dcol][urow];  // = WT[u0+urow][d0+dcol]
    half_t h = (half_t)x;
    half_t* o = out + (size_t)(u0 + urow) * KCAT + d0;
    o[dcol] = h;
    o[dcol + 1024] = h;
  }
}

// ---------- GEMM: C[m][n] = sum_k A[m][k] * Bt[n][k] ----------
// 128x128 tile, 4 waves each 64x64 (4x4 frags of mfma_f32_16x16x32_f16), BK=64.
// Single-buffered, 2 barriers per 64-K iter (same barrier density as R6, 2x the
// MFMA per drain). Tile = 128 rows x 64 halves = 1024 chunks of 16B; thread t
// stages chunks t+256s, s=0..3, per matrix.
// Swizzle: LDS chunk (row,pos) holds global chunk q = pos ^ (row&7).
enum { EP_F32 = 0, EP_QK = 1, EP_VT = 2 };

template <int MODE>
__global__ __launch_bounds__(256, 4) void k_gemm(
    const half_t* __restrict__ A, long long aBatch, int lda,
    const half_t* __restrict__ Bt, long long bBatch, int ldb,
    void* __restrict__ Cout, long long cBatch, int ldc, int K,
    half_t* __restrict__ CoutK) {
  __shared__ __align__(16) half_t As[128 * 64];
  __shared__ __align__(16) half_t Bs[128 * 64];
  const int t = threadIdx.x;
  const int z = blockIdx.z;
  A += (long long)z * aBatch;
  Bt += (long long)z * bBatch;
  const int m0 = blockIdx.y * 128, n0 = blockIdx.x * 128;

  const int w = t >> 6, l = t & 63;
  const int lr = l & 15, quad = l >> 4;
  const int wm = (w >> 1) * 64, wn = (w & 1) * 64;

  const floatx4 fz = {0.f, 0.f, 0.f, 0.f};
  floatx4 acc[4][4];
#pragma unroll
  for (int i = 0; i < 4; i++)
#pragma unroll
    for (int j = 0; j < 4; j++) acc[i][j] = fz;

  // staging pointers: chunk c = s*256+t -> row c>>3, lds pos c&7,
  // global col-chunk (c&7) ^ ((c>>3)&7)
  const half_t* Ap[4];
  const half_t* Bp[4];
  half_t* ldsA[4];
  half_t* ldsB[4];
#pragma unroll
  for (int s = 0; s < 4; s++) {
    int c = s * 256 + t;
    int row = c >> 3, gq = (c & 7) ^ ((c >> 3) & 7);
    Ap[s] = A + (long long)(m0 + row) * lda + gq * 8;
    Bp[s] = Bt + (long long)(n0 + row) * ldb + gq * 8;
    ldsA[s] = &As[(s * 256 + w * 64) * 8];  // wave-uniform; lane adds l*16B
    ldsB[s] = &Bs[(s * 256 + w * 64) * 8];
  }

  // fragment read positions: k-step s, quad-chunk q = s*4+quad,
  // pos p = q ^ (lr&7); addr = row*64 + p*8 halves
  const int p0 = quad ^ (lr & 7);
  const int p1 = (quad + 4) ^ (lr & 7);
  const int arow = (wm + lr) * 64, brow = (wn + lr) * 64;

  for (int kb = 0; kb < K; kb += 64) {
    __syncthreads();  // prev iter's frag reads done before overwrite
#pragma unroll
    for (int s = 0; s < 4; s++) {
      gload16(Ap[s] + kb, ldsA[s]);
      gload16(Bp[s] + kb, ldsB[s]);
    }
    __syncthreads();  // drains vmcnt -> tile visible
#pragma unroll
    for (int s = 0; s < 2; s++) {
      const int pp = s ? p1 : p0;
      short8 af[4], bfg[4];
#pragma unroll
      for (int j = 0; j < 4; j++) bfg[j] = *(const short8*)&Bs[brow + j * 1024 + pp * 8];
#pragma unroll
      for (int i = 0; i < 4; i++) af[i] = *(const short8*)&As[arow + i * 1024 + pp * 8];
#pragma unroll
      for (int i = 0; i < 4; i++)
#pragma unroll
        for (int j = 0; j < 4; j++)
          acc[i][j] = __builtin_amdgcn_mfma_f32_16x16x32_f16(af[i], bfg[j], acc[i][j], 0, 0, 0);
    }
  }

  // epilogue: D[row = quad*4 + r][col = lr] per (i,j) subtile
#pragma unroll
  for (int i = 0; i < 4; i++) {
#pragma unroll
    for (int j = 0; j < 4; j++) {
#pragma unroll
      for (int r = 0; r < 4; r++) {
        int grow = m0 + wm + i * 16 + quad * 4 + r;
        int gcol = n0 + wn + j * 16 + lr;
        float v = acc[i][j][r];
        if (MODE == EP_F32) {
          float* C = (float*)Cout + (long long)z * cBatch;
          C[(long long)grow * ldc + gcol] = v;
        } else if (MODE == EP_QK) {  // gcol in [0,2048); sel uniform per (block,j)
          int sel = gcol >> 10;
          int ucol = gcol & 1023;
          half_t h = (half_t)v;
          if (sel == 0) {        // Q = [qh | ql]
            half_t* pq = (half_t*)Cout + (long long)grow * KCAT;
            pq[ucol] = h;
            pq[ucol + 1024] = (half_t)(v - (float)h);
          } else {               // K = [kh | kh]
            half_t* pk = CoutK + (long long)grow * KCAT;
            pk[ucol] = h;
            pk[ucol + 1024] = h;
          }
        } else {  // EP_VT: V^T[b][u][s] = V[b*2048+s][u]
          half_t* C = (half_t*)Cout;
          int b = grow >> 11, s = grow & 2047;
          C[((long long)b * 1024 + gcol) * 2048 + s] = (half_t)v;
        }
      }
    }
  }
}

// ---------- softmax, in place: S row (fp32[2048]) -> P row (fp16[2048]) ----------
__global__ __launch_bounds__(256) void k_softmax(float* __restrict__ Sbuf) {
  long long row = blockIdx.x;  // 0..8191
  float* p = Sbuf + row * 2048;
  int t = threadIdx.x;
  float4 v0 = ((const float4*)p)[t];
  float4 v1 = ((const float4*)p)[t + 256];
  float m = fmaxf(fmaxf(fmaxf(v0.x, v0.y), fmaxf(v0.z, v0.w)),
                  fmaxf(fmaxf(v1.x, v1.y), fmaxf(v1.z, v1.w)));
  for (int off = 32; off; off >>= 1) m = fmaxf(m, __shfl_xor(m, off));
  __shared__ float red[8];
  int wv = t >> 6, ln = t & 63;
  if (ln == 0) red[wv] = m;
  __syncthreads();
  m = fmaxf(fmaxf(red[0], red[1]), fmaxf(red[2], red[3]));
  float e0 = __expf(v0.x - m), e1 = __expf(v0.y - m), e2 = __expf(v0.z - m), e3 = __expf(v0.w - m);
  float e4 = __expf(v1.x - m), e5 = __expf(v1.y - m), e6 = __expf(v1.z - m), e7 = __expf(v1.w - m);
  float s = ((e0 + e1) + (e2 + e3)) + ((e4 + e5) + (e6 + e7));
  for (int off = 32; off; off >>= 1) s += __shfl_xor(s, off);
  if (ln == 0) red[4 + wv] = s;
  __syncthreads();
  s = (red[4] + red[5]) + (red[6] + red[7]);
  float inv = 1.0f / s;
  uint2 w0, w1;
  w0.x = (unsigned)h2u((half_t)(e0 * inv)) | ((unsigned)h2u((half_t)(e1 * inv)) << 16);
  w0.y = (unsigned)h2u((half_t)(e2 * inv)) | ((unsigned)h2u((half_t)(e3 * inv)) << 16);
  w1.x = (unsigned)h2u((half_t)(e4 * inv)) | ((unsigned)h2u((half_t)(e5 * inv)) << 16);
  w1.y = (unsigned)h2u((half_t)(e6 * inv)) | ((unsigned)h2u((half_t)(e7 * inv)) << 16);
  ((uint2*)p)[t] = w0;         // fp16 elements 4t .. 4t+3
  ((uint2*)p)[t + 256] = w1;   // fp16 elements 1024+4t ..
}

// ---------- host launch ----------
extern "C" void kernel_launch(void* const* d_in, const int* in_sizes, int n_in,
                              void* d_out, int out_size, void* d_ws, size_t ws_size,
                              hipStream_t stream) {
  (void)in_sizes; (void)n_in; (void)out_size;
  if (ws_size < WS_NEED) return;  // output stays poisoned -> visible failure

  const float* X = (const float*)d_in[0];
  const float* Wq = (const float*)d_in[1];
  const float* Wk = (const float*)d_in[2];
  const float* Wv = (const float*)d_in[3];
  char* ws = (char*)d_ws;
  half_t* xcat = (half_t*)(ws + XCAT_OFF);
  half_t* wt = (half_t*)(ws + WT_OFF);
  float* Sbuf = (float*)(ws + S_OFF);
  half_t* qcat = (half_t*)(ws + QCAT_OFF);
  half_t* kcat = (half_t*)(ws + KCAT_OFF);
  half_t* vt = (half_t*)(ws + VT_OFF);
  float* out = (float*)d_out;

  // 1. split X and W (fp16)
  k_split_x<<<dim3(MX * 1024 / 256), dim3(256), 0, stream>>>(X, xcat);
  k_split_wt<<<dim3(16, 16, 3), dim3(256), 0, stream>>>(Wq, Wk, Wv, wt);

  // 2a. fused QK projection: M=8192, N=2048 (Wq|Wk rows), K=2048 (2-term)
  k_gemm<EP_QK><<<dim3(16, 64, 1), dim3(256), 0, stream>>>(
      xcat, 0LL, KCAT, wt, 0LL, KCAT, qcat, 0LL, 0, KCAT, kcat);

  // 2b. V projection: M=8192, N=1024, K=1024 (1-term: x_hi . Wv_hi)
  k_gemm<EP_VT><<<dim3(8, 64, 1), dim3(256), 0, stream>>>(
      xcat, 0LL, KCAT, wt + 2 * 1024 * KCAT, 0LL, KCAT, vt, 0LL, 0, 1024, nullptr);

  // 3. scores S = Q K^T (fp16 2-term), fp32 out: per batch M=N=2048
  k_gemm<EP_F32><<<dim3(16, 16, 4), dim3(256), 0, stream>>>(
      qcat, (long long)2048 * KCAT, KCAT, kcat, (long long)2048 * KCAT, KCAT,
      Sbuf, (long long)2048 * 2048, 2048, KCAT, nullptr);

  // 4. softmax in place (fp32 row -> fp16 row; row stride becomes 4096 halves)
  k_softmax<<<dim3(8192), dim3(256), 0, stream>>>(Sbuf);

  // 5. O = P V (plain fp16), fp32 out: per batch M=2048, N=1024, K=2048
  k_gemm<EP_F32><<<dim3(8, 16, 4), dim3(256), 0, stream>>>(
      (const half_t*)Sbuf, (long long)2048 * 4096, 4096,
      vt, (long long)1024 * 2048, 2048,
      out, (long long)2048 * 1024, 1024, 2048, nullptr);
}